// Round 1
// baseline (250.282 us; speedup 1.0000x reference)
//
#include <hip/hip_runtime.h>
#include <math.h>

#define T_LEN 200000
#define DIM   512
#define HID   512
#define KTOP  64
#define CAND_CAP 65536

// workspace byte offsets
#define OFF_ALPHA 0u           // T_LEN * 4 = 800000
#define OFF_HIST  800000u      // 256 u32
#define OFF_SCAL  801024u      // 16 u32: [0]=cand_cnt [1]=top_cnt [2]=sel_byte [3]=cnt_above [4]=need [5]=kth_key
#define OFF_CAND  801088u      // CAND_CAP u32
#define OFF_TIDX  1063232u     // 64 u32
#define OFF_TVAL  1063488u     // 64 f32

__device__ __forceinline__ unsigned monokey(float f) {
    unsigned u = __float_as_uint(f);
    return (u & 0x80000000u) ? ~u : (u | 0x80000000u);
}

__global__ void k_zero(unsigned* __restrict__ p, int n) {
    int i = blockIdx.x * blockDim.x + threadIdx.x;
    if (i < n) p[i] = 0u;
}

// ---- main 400MB kernel: alpha[i] = dot(fs[i], fea), fused msb-histogram ----
__global__ void k_alpha(const float* __restrict__ fs, const float* __restrict__ fea,
                        float* __restrict__ alpha, unsigned* __restrict__ ghist) {
    __shared__ unsigned lhist[256];
    int tid = threadIdx.x;
    lhist[tid] = 0u;                      // blockDim == 256
    __syncthreads();
    int lane = tid & 63;
    int wv   = tid >> 6;                  // 0..3
    const float4* fs4  = (const float4*)fs;
    const float4* fea4 = (const float4*)fea;
    float4 f0 = fea4[lane];
    float4 f1 = fea4[64 + lane];
    int stride = gridDim.x * 4;
    for (int row = blockIdx.x * 4 + wv; row < T_LEN; row += stride) {
        const float4* r4 = fs4 + (size_t)row * 128;
        float4 a = r4[lane];
        float4 b = r4[64 + lane];
        float s = a.x*f0.x + a.y*f0.y + a.z*f0.z + a.w*f0.w
                + b.x*f1.x + b.y*f1.y + b.z*f1.z + b.w*f1.w;
        for (int m = 32; m; m >>= 1) s += __shfl_xor(s, m, 64);
        if (lane == 0) {
            alpha[row] = s;
            atomicAdd(&lhist[monokey(s) >> 24], 1u);
        }
    }
    __syncthreads();
    if (lhist[tid]) atomicAdd(&ghist[tid], lhist[tid]);
}

// ---- find msb bucket containing rank-64 ----
__global__ void k_pick_bucket(const unsigned* __restrict__ ghist, unsigned* __restrict__ scal) {
    __shared__ unsigned lh[256];
    int tid = threadIdx.x;
    lh[tid] = ghist[tid];
    __syncthreads();
    if (tid == 0) {
        unsigned cum = 0; int b = 0;
        for (int x = 255; x >= 0; --x) {
            if (cum + lh[x] >= KTOP) { b = x; break; }
            cum += lh[x];
        }
        scal[2] = (unsigned)b;
        scal[3] = cum;               // cnt_above
        scal[4] = KTOP - cum;        // rank within bucket, 1..64
    }
}

// ---- collect candidate keys in selected bucket ----
__global__ void k_collect_cand(const float* __restrict__ alpha, unsigned* __restrict__ scal,
                               unsigned* __restrict__ cand) {
    unsigned b = scal[2];
    int stride = gridDim.x * blockDim.x;
    for (int i = blockIdx.x * blockDim.x + threadIdx.x; i < T_LEN; i += stride) {
        unsigned key = monokey(alpha[i]);
        if ((key >> 24) == b) {
            unsigned pos = atomicAdd(&scal[0], 1u);
            if (pos < CAND_CAP) cand[pos] = key;
        }
    }
}

// ---- radix-refine bytes 2..0 -> exact key of 64th largest ----
__global__ void k_refine(const unsigned* __restrict__ cand, unsigned* __restrict__ scal) {
    __shared__ unsigned hist[256];
    __shared__ unsigned sh_prefix, sh_rank;
    int tid = threadIdx.x;                // blockDim == 256
    if (tid == 0) { sh_prefix = scal[2] << 24; sh_rank = scal[4]; }
    __syncthreads();
    unsigned n = scal[0]; if (n > CAND_CAP) n = CAND_CAP;
    for (int shift = 16; shift >= 0; shift -= 8) {
        hist[tid] = 0u;
        __syncthreads();
        unsigned prefix = sh_prefix;
        unsigned maskc  = ~((1u << (shift + 8)) - 1u);
        for (unsigned i = tid; i < n; i += 256) {
            unsigned key = cand[i];
            if ((key & maskc) == prefix) atomicAdd(&hist[(key >> shift) & 255u], 1u);
        }
        __syncthreads();
        if (tid == 0) {
            unsigned r = sh_rank, cum = 0; int x;
            for (x = 255; x >= 0; --x) {
                if (cum + hist[x] >= r) break;
                cum += hist[x];
            }
            sh_prefix = prefix | ((unsigned)x << shift);
            sh_rank   = r - cum;
        }
        __syncthreads();
    }
    if (tid == 0) scal[5] = sh_prefix;
}

// ---- collect the 64 top indices/values ----
__global__ void k_collect_top(const float* __restrict__ alpha, unsigned* __restrict__ scal,
                              unsigned* __restrict__ tidx, float* __restrict__ tval) {
    unsigned kth = scal[5];
    int stride = gridDim.x * blockDim.x;
    for (int i = blockIdx.x * blockDim.x + threadIdx.x; i < T_LEN; i += stride) {
        float v = alpha[i];
        if (monokey(v) >= kth) {
            unsigned pos = atomicAdd(&scal[1], 1u);
            if (pos < KTOP) { tidx[pos] = (unsigned)i; tval[pos] = v; }
        }
    }
}

// ---- softmax weights, attn_h gather, prediction head + log_softmax ----
__global__ void k_attn_head(const float* __restrict__ hs, const float* __restrict__ fea,
                            const float* __restrict__ h, const float* __restrict__ Wout,
                            const float* __restrict__ bout,
                            const unsigned* __restrict__ tidx, const float* __restrict__ tval,
                            float* __restrict__ out) {
    __shared__ float wgt[KTOP];
    __shared__ int   sidx[KTOP];
    __shared__ float attn[HID];
    __shared__ float logit[8];
    int tid = threadIdx.x;                // blockDim == 512
    if (tid < KTOP) {                     // wave 0 entirely
        float v = tval[tid];
        float m = v;
        for (int d = 32; d; d >>= 1) m = fmaxf(m, __shfl_xor(m, d, 64));
        float e = expf(v - m);
        float s = e;
        for (int d = 32; d; d >>= 1) s += __shfl_xor(s, d, 64);
        wgt[tid]  = e / s;
        sidx[tid] = (int)tidx[tid];
    }
    __syncthreads();
    float acc = 0.f;
    for (int k = 0; k < KTOP; ++k)
        acc += wgt[k] * hs[(size_t)sidx[k] * HID + tid];
    attn[tid] = acc;
    __syncthreads();
    int wv = tid >> 6, lane = tid & 63;
    if (wv < 5) {
        float a = 0.f;
        for (int c = lane; c < 1537; c += 64) {
            float pv = (c < 512) ? fea[c] : (c < 1024) ? attn[c - 512]
                      : (c < 1536) ? h[c - 1024] : 64.0f;
            a += pv * Wout[wv * 1537 + c];
        }
        for (int d = 32; d; d >>= 1) a += __shfl_xor(a, d, 64);
        if (lane == 0) logit[wv] = a + bout[wv];
    }
    __syncthreads();
    if (tid == 0) {
        float m = logit[0];
        for (int l = 1; l < 5; ++l) m = fmaxf(m, logit[l]);
        float s = 0.f;
        for (int l = 0; l < 5; ++l) s += expf(logit[l] - m);
        float lse = m + logf(s);
        for (int l = 0; l < 5; ++l) out[l] = logit[l] - lse;
    }
}

// ---- fused single-step GRU: h_new directly ----
__global__ void k_gru(const float* __restrict__ w_ih, const float* __restrict__ w_hh,
                      const float* __restrict__ b_ih, const float* __restrict__ b_hh,
                      const float* __restrict__ fea, const float* __restrict__ h,
                      float* __restrict__ out) {
    int tid = threadIdx.x;                // blockDim == 256
    int tx  = tid & 15;
    int ty  = tid >> 4;                   // 0..15
    int j   = blockIdx.x * 16 + ty;       // hidden unit
    const float4* f4  = (const float4*)fea;
    const float4* h4  = (const float4*)h;
    const float4* wi4 = (const float4*)w_ih;
    const float4* wh4 = (const float4*)w_hh;
    int r0 = j, r1 = HID + j, r2 = 2 * HID + j;
    float gir = 0, giz = 0, gin = 0, ghr = 0, ghz = 0, ghn = 0;
    for (int it = 0; it < 8; ++it) {
        int c = tx + it * 16;             // float4 column 0..127
        float4 x = f4[c], hh = h4[c];
        float4 w;
        w = wi4[(size_t)r0 * 128 + c]; gir += w.x*x.x + w.y*x.y + w.z*x.z + w.w*x.w;
        w = wi4[(size_t)r1 * 128 + c]; giz += w.x*x.x + w.y*x.y + w.z*x.z + w.w*x.w;
        w = wi4[(size_t)r2 * 128 + c]; gin += w.x*x.x + w.y*x.y + w.z*x.z + w.w*x.w;
        w = wh4[(size_t)r0 * 128 + c]; ghr += w.x*hh.x + w.y*hh.y + w.z*hh.z + w.w*hh.w;
        w = wh4[(size_t)r1 * 128 + c]; ghz += w.x*hh.x + w.y*hh.y + w.z*hh.z + w.w*hh.w;
        w = wh4[(size_t)r2 * 128 + c]; ghn += w.x*hh.x + w.y*hh.y + w.z*hh.z + w.w*hh.w;
    }
    for (int d = 1; d < 16; d <<= 1) {
        gir += __shfl_xor(gir, d, 64);
        giz += __shfl_xor(giz, d, 64);
        gin += __shfl_xor(gin, d, 64);
        ghr += __shfl_xor(ghr, d, 64);
        ghz += __shfl_xor(ghz, d, 64);
        ghn += __shfl_xor(ghn, d, 64);
    }
    if (tx == 0) {
        float r = 1.f / (1.f + expf(-(gir + b_ih[r0] + ghr + b_hh[r0])));
        float z = 1.f / (1.f + expf(-(giz + b_ih[r1] + ghz + b_hh[r1])));
        float n = tanhf(gin + b_ih[r2] + r * (ghn + b_hh[r2]));
        out[5 + j] = (1.f - z) * n + z * h[j];
    }
}

extern "C" void kernel_launch(void* const* d_in, const int* in_sizes, int n_in,
                              void* d_out, int out_size, void* d_ws, size_t ws_size,
                              hipStream_t stream) {
    const float* fea  = (const float*)d_in[0];
    const float* h    = (const float*)d_in[1];
    const float* fs   = (const float*)d_in[2];
    const float* hs   = (const float*)d_in[3];
    const float* w_ih = (const float*)d_in[4];
    const float* w_hh = (const float*)d_in[5];
    const float* b_ih = (const float*)d_in[6];
    const float* b_hh = (const float*)d_in[7];
    const float* Wout = (const float*)d_in[8];
    const float* bout = (const float*)d_in[9];
    float* out = (float*)d_out;

    unsigned char* w = (unsigned char*)d_ws;
    float*    alpha = (float*)   (w + OFF_ALPHA);
    unsigned* ghist = (unsigned*)(w + OFF_HIST);
    unsigned* scal  = (unsigned*)(w + OFF_SCAL);
    unsigned* cand  = (unsigned*)(w + OFF_CAND);
    unsigned* tidx  = (unsigned*)(w + OFF_TIDX);
    float*    tval  = (float*)   (w + OFF_TVAL);

    // zero hist(256) + scalars(16) = 272 words
    k_zero<<<2, 256, 0, stream>>>(ghist, 272);
    // independent GRU branch (small)
    k_gru<<<32, 256, 0, stream>>>(w_ih, w_hh, b_ih, b_hh, fea, h, out);
    // dominant 400MB matvec + histogram
    k_alpha<<<2048, 256, 0, stream>>>(fs, fea, alpha, ghist);
    // exact top-64 selection
    k_pick_bucket<<<1, 256, 0, stream>>>(ghist, scal);
    k_collect_cand<<<256, 256, 0, stream>>>(alpha, scal, cand);
    k_refine<<<1, 256, 0, stream>>>(cand, scal);
    k_collect_top<<<256, 256, 0, stream>>>(alpha, scal, tidx, tval);
    // attention epilogue + head
    k_attn_head<<<1, 512, 0, stream>>>(hs, fea, h, Wout, bout, tidx, tval, out);
}

// Round 3
// 212.780 us; speedup vs baseline: 1.1762x; 1.1762x over previous
//
#include <hip/hip_runtime.h>
#include <math.h>

#define T_LEN 200000
#define DIM   512
#define HID   512
#define KTOP  64
#define CAND_CAP 131072   // global candidate buffer (expect ~15.7K on this data)

// workspace layout (bytes)
#define OFF_ALPHA 0u            // T_LEN * 4 = 800000
#define OFF_HIST  800000u       // 256 u32
#define OFF_CANDK 801024u       // CAND_CAP u32 keys
#define OFF_CANDI 1325312u      // CAND_CAP u32 indices

__device__ __forceinline__ unsigned monokey(float f) {
    unsigned u = __float_as_uint(f);
    return (u & 0x80000000u) ? ~u : (u | 0x80000000u);
}
__device__ __forceinline__ float unmonokey(unsigned k) {
    return __uint_as_float((k & 0x80000000u) ? (k & 0x7fffffffu) : ~k);
}

// ---- K1: zero histogram (block 0) + fused single-step GRU (64 blocks) ----
__global__ void k_pre(const float* __restrict__ w_ih, const float* __restrict__ w_hh,
                      const float* __restrict__ b_ih, const float* __restrict__ b_hh,
                      const float* __restrict__ fea, const float* __restrict__ h,
                      unsigned* __restrict__ ghist, float* __restrict__ out) {
    int tid = threadIdx.x;                 // 256
    if (blockIdx.x == 0 && tid < 256) ghist[tid] = 0u;

    int tx = tid & 31;                     // 32 lanes per hidden unit
    int ty = tid >> 5;                     // 8 units per block
    int j  = blockIdx.x * 8 + ty;          // hidden unit 0..511
    const float4* f4  = (const float4*)fea;
    const float4* h4  = (const float4*)h;
    const float4* wi4 = (const float4*)w_ih;
    const float4* wh4 = (const float4*)w_hh;
    int r0 = j, r1 = HID + j, r2 = 2 * HID + j;
    float gir = 0, giz = 0, gin = 0, ghr = 0, ghz = 0, ghn = 0;
    #pragma unroll
    for (int it = 0; it < 4; ++it) {
        int c = tx + it * 32;              // float4 column 0..127
        float4 x = f4[c], hh = h4[c];
        float4 w;
        w = wi4[(size_t)r0 * 128 + c]; gir += w.x*x.x + w.y*x.y + w.z*x.z + w.w*x.w;
        w = wi4[(size_t)r1 * 128 + c]; giz += w.x*x.x + w.y*x.y + w.z*x.z + w.w*x.w;
        w = wi4[(size_t)r2 * 128 + c]; gin += w.x*x.x + w.y*x.y + w.z*x.z + w.w*x.w;
        w = wh4[(size_t)r0 * 128 + c]; ghr += w.x*hh.x + w.y*hh.y + w.z*hh.z + w.w*hh.w;
        w = wh4[(size_t)r1 * 128 + c]; ghz += w.x*hh.x + w.y*hh.y + w.z*hh.z + w.w*hh.w;
        w = wh4[(size_t)r2 * 128 + c]; ghn += w.x*hh.x + w.y*hh.y + w.z*hh.z + w.w*hh.w;
    }
    #pragma unroll
    for (int d = 16; d; d >>= 1) {
        gir += __shfl_xor(gir, d, 64);
        giz += __shfl_xor(giz, d, 64);
        gin += __shfl_xor(gin, d, 64);
        ghr += __shfl_xor(ghr, d, 64);
        ghz += __shfl_xor(ghz, d, 64);
        ghn += __shfl_xor(ghn, d, 64);
    }
    if (tx == 0) {
        float r = 1.f / (1.f + expf(-(gir + b_ih[r0] + ghr + b_hh[r0])));
        float z = 1.f / (1.f + expf(-(giz + b_ih[r1] + ghz + b_hh[r1])));
        float n = tanhf(gin + b_ih[r2] + r * (ghn + b_hh[r2]));
        out[5 + j] = (1.f - z) * n + z * h[j];
    }
}

// ---- K2: alpha[i] = dot(fs[i], fea) + fused msb-byte histogram (400 MB) ----
__global__ void k_alpha(const float* __restrict__ fs, const float* __restrict__ fea,
                        float* __restrict__ alpha, unsigned* __restrict__ ghist) {
    __shared__ unsigned lhist[256];
    int tid = threadIdx.x;                 // 256
    lhist[tid] = 0u;
    __syncthreads();
    int lane = tid & 63;
    int wv   = tid >> 6;                   // 0..3
    const float4* fs4  = (const float4*)fs;
    const float4* fea4 = (const float4*)fea;
    float4 f0 = fea4[lane];
    float4 f1 = fea4[64 + lane];
    int stride = gridDim.x * 4;
    for (int row = blockIdx.x * 4 + wv; row < T_LEN; row += stride) {
        const float4* r4 = fs4 + (size_t)row * 128;
        float4 a = r4[lane];
        float4 b = r4[64 + lane];
        float s = a.x*f0.x + a.y*f0.y + a.z*f0.z + a.w*f0.w
                + b.x*f1.x + b.y*f1.y + b.z*f1.z + b.w*f1.w;
        #pragma unroll
        for (int m = 32; m; m >>= 1) s += __shfl_xor(s, m, 64);
        if (lane == 0) {
            alpha[row] = s;
            atomicAdd(&lhist[monokey(s) >> 24], 1u);
        }
    }
    __syncthreads();
    if (lhist[tid]) atomicAdd(&ghist[tid], lhist[tid]);
}

// ---- K3: selection (global cand buffer) + softmax + attn + head ----
__global__ __launch_bounds__(1024)
void k_post(const float* __restrict__ alpha, const unsigned* __restrict__ ghist,
            unsigned* __restrict__ candk, unsigned* __restrict__ candi,
            const float* __restrict__ hs, const float* __restrict__ fea,
            const float* __restrict__ h, const float* __restrict__ Wout,
            const float* __restrict__ bout, float* __restrict__ out) {
    __shared__ unsigned s_hist[256];
    __shared__ unsigned s_cnt, s_top, s_bucket, s_rank, s_pref;
    __shared__ float    s_val[96];
    __shared__ int      s_sidx[96];
    __shared__ float    s_wgt[KTOP];
    __shared__ float    s_attn2[2][HID];
    __shared__ float    s_attn[HID];
    __shared__ float    s_logit[8];
    int tid = threadIdx.x;                 // 1024

    if (tid < 256) s_hist[tid] = ghist[tid];
    if (tid == 0) { s_cnt = 0u; s_top = 0u; }
    __syncthreads();
    if (tid == 0) {
        unsigned cum = 0; int b = 0;
        for (int x = 255; x >= 0; --x) {
            if (cum + s_hist[x] >= KTOP) { b = x; break; }
            cum += s_hist[x];
        }
        s_bucket = (unsigned)b;
        s_rank   = KTOP - cum;             // 1..64
        s_pref   = (unsigned)b << 24;
    }
    __syncthreads();
    unsigned bucket = s_bucket;

    // scan alpha: bucket==b -> global cand; bucket>b -> directly into top list
    const float4* a4 = (const float4*)alpha;
    for (int i = tid; i < T_LEN / 4; i += 1024) {
        float4 v = a4[i];
        float vv[4] = {v.x, v.y, v.z, v.w};
        #pragma unroll
        for (int c = 0; c < 4; ++c) {
            unsigned key = monokey(vv[c]);
            unsigned kb  = key >> 24;
            if (kb == bucket) {
                unsigned p = atomicAdd(&s_cnt, 1u);
                if (p < CAND_CAP) { candk[p] = key; candi[p] = (unsigned)(i * 4 + c); }
            } else if (kb > bucket) {
                unsigned p = atomicAdd(&s_top, 1u);
                if (p < 96) { s_sidx[p] = i * 4 + c; s_val[p] = vv[c]; }
            }
        }
    }
    __syncthreads();
    unsigned n = s_cnt; if (n > CAND_CAP) n = CAND_CAP;

    // radix-refine bytes 2..0 -> exact 64th key
    for (int shift = 16; shift >= 0; shift -= 8) {
        if (tid < 256) s_hist[tid] = 0u;
        __syncthreads();
        unsigned pref  = s_pref;
        unsigned maskc = ~((1u << (shift + 8)) - 1u);
        for (unsigned i = tid; i < n; i += 1024) {
            unsigned key = candk[i];
            if ((key & maskc) == pref) atomicAdd(&s_hist[(key >> shift) & 255u], 1u);
        }
        __syncthreads();
        if (tid == 0) {
            unsigned r = s_rank, cum = 0; int x;
            for (x = 255; x >= 0; --x) {
                if (cum + s_hist[x] >= r) break;
                cum += s_hist[x];
            }
            s_pref = pref | ((unsigned)x << shift);
            s_rank = r - cum;
        }
        __syncthreads();
    }
    unsigned kth = s_pref;

    // in-bucket extraction: key >= kth joins the top list
    for (unsigned i = tid; i < n; i += 1024) {
        unsigned key = candk[i];
        if (key >= kth) {
            unsigned p = atomicAdd(&s_top, 1u);
            if (p < 96) { s_sidx[p] = (int)candi[i]; s_val[p] = unmonokey(key); }
        }
    }
    __syncthreads();

    // softmax over the 64 values (wave 0)
    if (tid < KTOP) {
        float v = s_val[tid];
        float m = v;
        #pragma unroll
        for (int d = 32; d; d >>= 1) m = fmaxf(m, __shfl_xor(m, d, 64));
        float e = expf(v - m);
        float s = e;
        #pragma unroll
        for (int d = 32; d; d >>= 1) s += __shfl_xor(s, d, 64);
        s_wgt[tid] = e / s;
    }
    __syncthreads();

    // attn_h[col] = sum_k wgt[k] * hs[idx[k]][col]; two deterministic partials
    {
        int col = tid & (HID - 1);
        int g   = tid >> 9;                // 0 or 1
        float acc = 0.f;
        #pragma unroll 4
        for (int k = g * 32; k < g * 32 + 32; ++k)
            acc += s_wgt[k] * hs[(size_t)s_sidx[k] * HID + col];
        s_attn2[g][col] = acc;
    }
    __syncthreads();
    if (tid < HID) s_attn[tid] = s_attn2[0][tid] + s_attn2[1][tid];
    __syncthreads();

    // head: 5 logits over concat(fea, attn, h, 64.0) + log_softmax
    int wv = tid >> 6, lane = tid & 63;
    if (wv < 5) {
        float a = 0.f;
        for (int c = lane; c < 1537; c += 64) {
            float pv = (c < 512) ? fea[c] : (c < 1024) ? s_attn[c - 512]
                      : (c < 1536) ? h[c - 1024] : 64.0f;
            a += pv * Wout[wv * 1537 + c];
        }
        #pragma unroll
        for (int d = 32; d; d >>= 1) a += __shfl_xor(a, d, 64);
        if (lane == 0) s_logit[wv] = a + bout[wv];
    }
    __syncthreads();
    if (tid == 0) {
        float m = s_logit[0];
        for (int l = 1; l < 5; ++l) m = fmaxf(m, s_logit[l]);
        float s = 0.f;
        for (int l = 0; l < 5; ++l) s += expf(s_logit[l] - m);
        float lse = m + logf(s);
        for (int l = 0; l < 5; ++l) out[l] = s_logit[l] - lse;
    }
}

extern "C" void kernel_launch(void* const* d_in, const int* in_sizes, int n_in,
                              void* d_out, int out_size, void* d_ws, size_t ws_size,
                              hipStream_t stream) {
    const float* fea  = (const float*)d_in[0];
    const float* h    = (const float*)d_in[1];
    const float* fs   = (const float*)d_in[2];
    const float* hs   = (const float*)d_in[3];
    const float* w_ih = (const float*)d_in[4];
    const float* w_hh = (const float*)d_in[5];
    const float* b_ih = (const float*)d_in[6];
    const float* b_hh = (const float*)d_in[7];
    const float* Wout = (const float*)d_in[8];
    const float* bout = (const float*)d_in[9];
    float* out = (float*)d_out;

    unsigned char* w = (unsigned char*)d_ws;
    float*    alpha = (float*)   (w + OFF_ALPHA);
    unsigned* ghist = (unsigned*)(w + OFF_HIST);
    unsigned* candk = (unsigned*)(w + OFF_CANDK);
    unsigned* candi = (unsigned*)(w + OFF_CANDI);

    k_pre  <<<64,   256, 0, stream>>>(w_ih, w_hh, b_ih, b_hh, fea, h, ghist, out);
    k_alpha<<<2048, 256, 0, stream>>>(fs, fea, alpha, ghist);
    k_post <<<1,   1024, 0, stream>>>(alpha, ghist, candk, candi, hs, fea, h, Wout, bout, out);
}

// Round 4
// 161.122 us; speedup vs baseline: 1.5534x; 1.3206x over previous
//
#include <hip/hip_runtime.h>
#include <math.h>

#define T_LEN 200000
#define DIM   512
#define HID   512
#define KTOP  64
#define NBIN  4096          // top-12 monokey bits
#define CAPB  4096          // in-bucket candidate capacity (expect ~60)

// workspace layout (bytes)
#define OFF_ALPHA 0u        // T_LEN * 4 = 800000
#define OFF_HIST  800000u   // NBIN u32 = 16384

__device__ __forceinline__ unsigned monokey(float f) {
    unsigned u = __float_as_uint(f);
    return (u & 0x80000000u) ? ~u : (u | 0x80000000u);
}
__device__ __forceinline__ float unmonokey(unsigned k) {
    return __uint_as_float((k & 0x80000000u) ? (k & 0x7fffffffu) : ~k);
}

// ---- K1: blocks 0..63 GRU; blocks 64..2111 alpha matvec + 4096-bin hist ----
__global__ void k_main(const float* __restrict__ fs, const float* __restrict__ fea,
                       const float* __restrict__ h,
                       const float* __restrict__ w_ih, const float* __restrict__ w_hh,
                       const float* __restrict__ b_ih, const float* __restrict__ b_hh,
                       float* __restrict__ alpha, unsigned* __restrict__ ghist,
                       float* __restrict__ out) {
    int tid = threadIdx.x;                 // 256

    if (blockIdx.x < 64) {                 // ---- GRU branch ----
        int tx = tid & 31;
        int ty = tid >> 5;
        int j  = blockIdx.x * 8 + ty;      // hidden unit
        const float4* f4  = (const float4*)fea;
        const float4* h4  = (const float4*)h;
        const float4* wi4 = (const float4*)w_ih;
        const float4* wh4 = (const float4*)w_hh;
        int r0 = j, r1 = HID + j, r2 = 2 * HID + j;
        float gir = 0, giz = 0, gin = 0, ghr = 0, ghz = 0, ghn = 0;
        #pragma unroll
        for (int it = 0; it < 4; ++it) {
            int c = tx + it * 32;
            float4 x = f4[c], hh = h4[c];
            float4 w;
            w = wi4[(size_t)r0 * 128 + c]; gir += w.x*x.x + w.y*x.y + w.z*x.z + w.w*x.w;
            w = wi4[(size_t)r1 * 128 + c]; giz += w.x*x.x + w.y*x.y + w.z*x.z + w.w*x.w;
            w = wi4[(size_t)r2 * 128 + c]; gin += w.x*x.x + w.y*x.y + w.z*x.z + w.w*x.w;
            w = wh4[(size_t)r0 * 128 + c]; ghr += w.x*hh.x + w.y*hh.y + w.z*hh.z + w.w*hh.w;
            w = wh4[(size_t)r1 * 128 + c]; ghz += w.x*hh.x + w.y*hh.y + w.z*hh.z + w.w*hh.w;
            w = wh4[(size_t)r2 * 128 + c]; ghn += w.x*hh.x + w.y*hh.y + w.z*hh.z + w.w*hh.w;
        }
        #pragma unroll
        for (int d = 16; d; d >>= 1) {
            gir += __shfl_xor(gir, d, 64);
            giz += __shfl_xor(giz, d, 64);
            gin += __shfl_xor(gin, d, 64);
            ghr += __shfl_xor(ghr, d, 64);
            ghz += __shfl_xor(ghz, d, 64);
            ghn += __shfl_xor(ghn, d, 64);
        }
        if (tx == 0) {
            float r = 1.f / (1.f + expf(-(gir + b_ih[r0] + ghr + b_hh[r0])));
            float z = 1.f / (1.f + expf(-(giz + b_ih[r1] + ghz + b_hh[r1])));
            float n = tanhf(gin + b_ih[r2] + r * (ghn + b_hh[r2]));
            out[5 + j] = (1.f - z) * n + z * h[j];
        }
        return;
    }

    // ---- alpha branch ----
    __shared__ unsigned lhist[NBIN];       // 16 KB -> still 8 blocks/CU
    #pragma unroll
    for (int i = 0; i < NBIN / 256; ++i) lhist[tid + i * 256] = 0u;
    __syncthreads();

    int vb   = blockIdx.x - 64;            // 0..2047
    int lane = tid & 63;
    int wv   = tid >> 6;
    const float4* fs4  = (const float4*)fs;
    const float4* fea4 = (const float4*)fea;
    float4 f0 = fea4[lane];
    float4 f1 = fea4[64 + lane];
    const int stride = 2048 * 4;           // 8192 rows
    int row = vb * 4 + wv;
    // 2-row unroll for MLP
    for (; row + stride < T_LEN; row += 2 * stride) {
        const float4* ra = fs4 + (size_t)row * 128;
        const float4* rb = fs4 + (size_t)(row + stride) * 128;
        float4 a0 = ra[lane], a1 = ra[64 + lane];
        float4 b0 = rb[lane], b1 = rb[64 + lane];
        float sa = a0.x*f0.x + a0.y*f0.y + a0.z*f0.z + a0.w*f0.w
                 + a1.x*f1.x + a1.y*f1.y + a1.z*f1.z + a1.w*f1.w;
        float sb = b0.x*f0.x + b0.y*f0.y + b0.z*f0.z + b0.w*f0.w
                 + b1.x*f1.x + b1.y*f1.y + b1.z*f1.z + b1.w*f1.w;
        #pragma unroll
        for (int m = 32; m; m >>= 1) {
            sa += __shfl_xor(sa, m, 64);
            sb += __shfl_xor(sb, m, 64);
        }
        if (lane == 0) {
            alpha[row] = sa;
            alpha[row + stride] = sb;
            atomicAdd(&lhist[monokey(sa) >> 20], 1u);
            atomicAdd(&lhist[monokey(sb) >> 20], 1u);
        }
    }
    if (row < T_LEN) {
        const float4* ra = fs4 + (size_t)row * 128;
        float4 a0 = ra[lane], a1 = ra[64 + lane];
        float sa = a0.x*f0.x + a0.y*f0.y + a0.z*f0.z + a0.w*f0.w
                 + a1.x*f1.x + a1.y*f1.y + a1.z*f1.z + a1.w*f1.w;
        #pragma unroll
        for (int m = 32; m; m >>= 1) sa += __shfl_xor(sa, m, 64);
        if (lane == 0) {
            alpha[row] = sa;
            atomicAdd(&lhist[monokey(sa) >> 20], 1u);
        }
    }
    __syncthreads();
    #pragma unroll
    for (int i = 0; i < NBIN / 256; ++i) {
        unsigned c = lhist[tid + i * 256];
        if (c) atomicAdd(&ghist[tid + i * 256], c);
    }
}

// ---- K2: selection + softmax + attn + head + log_softmax (1 block) ----
__global__ __launch_bounds__(1024)
void k_post(const float* __restrict__ alpha, const unsigned* __restrict__ ghist,
            const float* __restrict__ hs, const float* __restrict__ fea,
            const float* __restrict__ h, const float* __restrict__ Wout,
            const float* __restrict__ bout, float* __restrict__ out) {
    __shared__ unsigned s_h[NBIN];         // 16 KB
    __shared__ unsigned s_c[1024];         // 4 KB coarse-4 sums
    __shared__ unsigned s_coarse[64];
    __shared__ unsigned s_ck[CAPB];        // 16 KB in-bucket keys
    __shared__ unsigned s_ci[CAPB];        // 16 KB in-bucket idx
    __shared__ unsigned s_nc, s_top, s_bucket, s_rank, s_kth;
    __shared__ float    s_val[96];
    __shared__ int      s_sidx[96];
    __shared__ float    s_wgt[KTOP];
    __shared__ float    s_attn2[2][HID];
    __shared__ float    s_attn[HID];
    __shared__ float    s_logit[8];
    int tid = threadIdx.x;                 // 1024

    for (int i = tid; i < NBIN; i += 1024) s_h[i] = ghist[i];
    if (tid == 0) { s_nc = 0u; s_top = 0u; }
    __syncthreads();
    s_c[tid] = s_h[4 * tid] + s_h[4 * tid + 1] + s_h[4 * tid + 2] + s_h[4 * tid + 3];
    __syncthreads();
    if (tid < 64) {
        unsigned cc = 0;
        #pragma unroll
        for (int j = 0; j < 16; ++j) cc += s_c[tid * 16 + j];
        s_coarse[tid] = cc;
    }
    __syncthreads();
    if (tid == 0) {
        unsigned cum = 0; int ch = 0;
        for (int x = 63; x >= 0; --x) {
            if (cum + s_coarse[x] >= KTOP) { ch = x; break; }
            cum += s_coarse[x];
        }
        int b = ch * 64;
        for (int x = ch * 64 + 63; x >= ch * 64; --x) {
            if (cum + s_h[x] >= KTOP) { b = x; break; }
            cum += s_h[x];
        }
        s_bucket = (unsigned)b;
        s_rank   = KTOP - cum;             // 1..bincount
    }
    __syncthreads();
    unsigned bucket = s_bucket;

    // scan alpha: bin > bucket -> top list; bin == bucket -> candidates
    const float4* a4 = (const float4*)alpha;
    for (int i = tid; i < T_LEN / 4; i += 1024) {
        float4 v = a4[i];
        float vv[4] = {v.x, v.y, v.z, v.w};
        #pragma unroll
        for (int c = 0; c < 4; ++c) {
            unsigned key = monokey(vv[c]);
            unsigned kb  = key >> 20;
            if (kb == bucket) {
                unsigned p = atomicAdd(&s_nc, 1u);
                if (p < CAPB) { s_ck[p] = key; s_ci[p] = (unsigned)(i * 4 + c); }
            } else if (kb > bucket) {
                unsigned p = atomicAdd(&s_top, 1u);
                if (p < 96) { s_sidx[p] = i * 4 + c; s_val[p] = vv[c]; }
            }
        }
    }
    __syncthreads();
    unsigned n = s_nc; if (n > CAPB) n = CAPB;
    unsigned r = s_rank;

    // exact kth among in-bucket candidates: O(n^2), n ~ 60
    for (unsigned i = tid; i < n; i += 1024) {
        unsigned k0 = s_ck[i];
        unsigned gt = 0, eq = 0;
        for (unsigned j = 0; j < n; ++j) {
            unsigned kj = s_ck[j];
            gt += (kj > k0);
            eq += (kj == k0);
        }
        if (gt < r && r <= gt + eq) s_kth = k0;
    }
    __syncthreads();
    unsigned kth = s_kth;
    for (unsigned i = tid; i < n; i += 1024) {
        unsigned k0 = s_ck[i];
        if (k0 >= kth) {
            unsigned p = atomicAdd(&s_top, 1u);
            if (p < 96) { s_sidx[p] = (int)s_ci[i]; s_val[p] = unmonokey(k0); }
        }
    }
    __syncthreads();

    // softmax over 64 values (wave 0)
    if (tid < KTOP) {
        float v = s_val[tid];
        float m = v;
        #pragma unroll
        for (int d = 32; d; d >>= 1) m = fmaxf(m, __shfl_xor(m, d, 64));
        float e = expf(v - m);
        float s = e;
        #pragma unroll
        for (int d = 32; d; d >>= 1) s += __shfl_xor(s, d, 64);
        s_wgt[tid] = e / s;
    }
    __syncthreads();

    // attn_h[col] = sum_k wgt[k]*hs[idx[k]][col]; 2 deterministic partials
    {
        int col = tid & (HID - 1);
        int g   = tid >> 9;
        float acc = 0.f;
        #pragma unroll 4
        for (int k = g * 32; k < g * 32 + 32; ++k)
            acc += s_wgt[k] * hs[(size_t)s_sidx[k] * HID + col];
        s_attn2[g][col] = acc;
    }
    __syncthreads();
    if (tid < HID) s_attn[tid] = s_attn2[0][tid] + s_attn2[1][tid];
    __syncthreads();

    // head: 5 logits over concat(fea, attn, h, 64.0) + log_softmax
    int wv = tid >> 6, lane = tid & 63;
    if (wv < 5) {
        float a = 0.f;
        for (int c = lane; c < 1537; c += 64) {
            float pv = (c < 512) ? fea[c] : (c < 1024) ? s_attn[c - 512]
                      : (c < 1536) ? h[c - 1024] : 64.0f;
            a += pv * Wout[wv * 1537 + c];
        }
        #pragma unroll
        for (int d = 32; d; d >>= 1) a += __shfl_xor(a, d, 64);
        if (lane == 0) s_logit[wv] = a + bout[wv];
    }
    __syncthreads();
    if (tid == 0) {
        float m = s_logit[0];
        for (int l = 1; l < 5; ++l) m = fmaxf(m, s_logit[l]);
        float s = 0.f;
        for (int l = 0; l < 5; ++l) s += expf(s_logit[l] - m);
        float lse = m + logf(s);
        for (int l = 0; l < 5; ++l) out[l] = s_logit[l] - lse;
    }
}

extern "C" void kernel_launch(void* const* d_in, const int* in_sizes, int n_in,
                              void* d_out, int out_size, void* d_ws, size_t ws_size,
                              hipStream_t stream) {
    const float* fea  = (const float*)d_in[0];
    const float* h    = (const float*)d_in[1];
    const float* fs   = (const float*)d_in[2];
    const float* hs   = (const float*)d_in[3];
    const float* w_ih = (const float*)d_in[4];
    const float* w_hh = (const float*)d_in[5];
    const float* b_ih = (const float*)d_in[6];
    const float* b_hh = (const float*)d_in[7];
    const float* Wout = (const float*)d_in[8];
    const float* bout = (const float*)d_in[9];
    float* out = (float*)d_out;

    unsigned char* w = (unsigned char*)d_ws;
    float*    alpha = (float*)   (w + OFF_ALPHA);
    unsigned* ghist = (unsigned*)(w + OFF_HIST);

    hipMemsetAsync(ghist, 0, NBIN * sizeof(unsigned), stream);
    k_main<<<2112, 256, 0, stream>>>(fs, fea, h, w_ih, w_hh, b_ih, b_hh, alpha, ghist, out);
    k_post<<<1,   1024, 0, stream>>>(alpha, ghist, hs, fea, h, Wout, bout, out);
}